// Round 7
// baseline (6050.538 us; speedup 1.0000x reference)
//
#include <hip/hip_runtime.h>
#include <hip/hip_bf16.h>
#include <math.h>

#define B_ 8
#define S_ 4096
#define D_ 768
#define NH_ 4
#define DH_ 192
#define NTOT_ 768   // 4*DH_

typedef __attribute__((ext_vector_type(8))) short short8;
typedef __attribute__((ext_vector_type(4))) float floatx4;
typedef __attribute__((ext_vector_type(4))) short short4v;
typedef __attribute__((ext_vector_type(4))) unsigned int uint4v;
typedef _Float16 f16;

__device__ __forceinline__ short f2bs(float f) {
  union { float f; unsigned u; } v; v.f = f;
  unsigned r = v.u + 0x7FFFu + ((v.u >> 16) & 1u);
  return (short)(r >> 16);
}
__device__ __forceinline__ float bs2f(unsigned short s) {
  union { unsigned u; float f; } v; v.u = ((unsigned)s) << 16;
  return v.f;
}
__device__ __forceinline__ unsigned packh2(float lo, float hi) {
  union { f16 h[2]; unsigned u; } x;
  x.h[0] = (f16)lo; x.h[1] = (f16)hi;
  return x.u;
}

// forced v_dot2_f32_f16 (f32 accumulate)
__device__ __forceinline__ float DOT2(unsigned r, unsigned y, float acc) {
  asm("v_dot2_f32_f16 %0, %1, %2, %0" : "+v"(acc) : "v"(r), "v"(y));
  return acc;
}

// quad-perm DPP (register-only cross-lane within quad)
template<int CTRL>
__device__ __forceinline__ float qperm(float x) {
  return __int_as_float(__builtin_amdgcn_mov_dpp(__float_as_int(x), CTRL, 0xf, 0xf, true));
}

// ---------------- K0: weights -> bf16, fragment-friendly [hg][o][d] ----------------
__global__ __launch_bounds__(256) void wconv_kernel(
    const float* __restrict__ wf, const float* __restrict__ wi,
    const float* __restrict__ wz, const float* __restrict__ wo,
    short* __restrict__ Wbf)
{
  int idx = blockIdx.x * 256 + threadIdx.x;      // < 16*36864
  int hg = idx / (DH_ * DH_);
  int r  = idx % (DH_ * DH_);
  int h = hg >> 2, g = hg & 3;
  const float* W = (g == 0) ? wf : (g == 1) ? wi : (g == 2) ? wz : wo;
  Wbf[idx] = f2bs(W[(size_t)h * DH_ * DH_ + r]);
}

// ---------------- K1: depthwise causal conv + SiLU; also bf16 copy of x ----------------
__global__ __launch_bounds__(256) void conv_silu_kernel(
    const float* __restrict__ x, const float* __restrict__ cw, const float* __restrict__ cb,
    short* __restrict__ xb, short* __restrict__ xcb)
{
  const int b  = blockIdx.x / (S_ / 64);
  const int s0 = (blockIdx.x % (S_ / 64)) * 64;
  const int tid = threadIdx.x;
  float wv[3][4], bias[3], win[3][3];
  for (int j = 0; j < 3; ++j) {
    int d = tid + j * 256;
    for (int k = 0; k < 4; ++k) wv[j][k] = cw[d * 4 + k];
    bias[j] = cb[d];
    for (int p = 0; p < 3; ++p) {
      int s = s0 - 3 + p;
      win[j][p] = (s >= 0) ? x[((size_t)b * S_ + s) * D_ + d] : 0.f;
    }
  }
  for (int i = 0; i < 64; ++i) {
    size_t base = ((size_t)b * S_ + (s0 + i)) * D_;
    for (int j = 0; j < 3; ++j) {
      int d = tid + j * 256;
      float xc = x[base + d];
      float a = bias[j] + win[j][0] * wv[j][0] + win[j][1] * wv[j][1]
                        + win[j][2] * wv[j][2] + xc * wv[j][3];
      float sv = a / (1.f + __expf(-a));
      xb[base + d]  = f2bs(xc);
      xcb[base + d] = f2bs(sv);
      win[j][0] = win[j][1]; win[j][1] = win[j][2]; win[j][2] = xc;
    }
  }
}

// ---------------- K2: headwise projections -> P[h][b][s][e*4+g] (bf16) ----------------
__global__ __launch_bounds__(256) void proj_kernel(
    const short* __restrict__ xb, const short* __restrict__ xcb,
    const short* __restrict__ Wbf, short* __restrict__ P)
{
  const int hg = blockIdx.y;
  const int h = hg >> 2, g = hg & 3;
  const short* A  = (g < 2) ? xcb : xb;           // gi,gf from conv(x); gz,go from x
  const short* Wb = Wbf + (size_t)hg * (DH_ * DH_);
  const int tid = threadIdx.x, w = tid >> 6, l = tid & 63;
  const int l15 = l & 15, lg = l >> 4;
  const int R0 = blockIdx.x * 256 + w * 64;

  for (int mp = 0; mp < 2; ++mp) {
    const int rb0 = R0 + mp * 32;
    floatx4 acc[2][12];
    for (int u = 0; u < 2; ++u)
      for (int nt = 0; nt < 12; ++nt) acc[u][nt] = (floatx4){0.f, 0.f, 0.f, 0.f};
    const short* Ar = A + (size_t)(rb0 + l15) * D_ + h * DH_ + lg * 8;
    const short* Bp = Wb + l15 * DH_ + lg * 8;
    for (int kk = 0; kk < 6; ++kk) {
      short8 a0 = *(const short8*)(Ar + kk * 32);
      short8 a1 = *(const short8*)(Ar + (size_t)16 * D_ + kk * 32);
      for (int nt = 0; nt < 12; ++nt) {
        short8 bf = *(const short8*)(Bp + nt * 16 * DH_ + kk * 32);
        acc[0][nt] = __builtin_amdgcn_mfma_f32_16x16x32_bf16(a0, bf, acc[0][nt], 0, 0, 0);
        acc[1][nt] = __builtin_amdgcn_mfma_f32_16x16x32_bf16(a1, bf, acc[1][nt], 0, 0, 0);
      }
    }
    for (int u = 0; u < 2; ++u) {
      for (int q = 0; q < 4; ++q) {
        int row = rb0 + u * 16 + lg * 4 + q;
        int s = row & (S_ - 1);
        int bb = row >> 12;
        // packed gate-interleaved layout: column e*4 + g, e = l15 + nt*16
        size_t ob = (((size_t)h * B_ + bb) * S_ + s) * NTOT_ + l15 * 4 + g;
        for (int nt = 0; nt < 12; ++nt) P[ob + nt * 64] = f2bs(acc[u][nt][q]);
      }
    }
  }
}

// ---------------- K3: sequential sLSTM scan (1024 threads/chain) ----------------
// WG = 1024 threads = 16 waves; occupancy lattice is {16 waves/CU (128 VGPR),
// 32 (64 VGPR)} -> compiler should pick 128, fitting R (72 dwords/lane) fully.
// Quad Q = tid>>2 owns outputs (g = Q>>6, e = (Q&63)*3 + j, j=0..2); lane u = tid&3
// owns k-quarter [48u, 48u+48). Per step: 6x ds_read_b128 of y quarter ->
// 72 dot2 -> quad butterfly -> raw exchange in LDS -> gate math (quad-redundant,
// e = Q for Q<192) -> y + history write. Two barriers/step.
__global__ __launch_bounds__(1024) void scan_kernel(
    short* P_, const float* __restrict__ rk, const float* __restrict__ rb)
{
  const int bid = blockIdx.x;          // 0..31: chain; h = bid>>3, b = bid&7
  const int h = bid >> 3;
  const int tid = threadIdx.x;         // 0..1023
  const int Q = tid >> 2, u = tid & 3;
  const int g = Q >> 6;                // gate column for dot phase
  const int e3 = (Q & 63) * 3;         // base element of this quad's 3 outputs

  __shared__ __align__(16) f16 y_lds[DH_];
  __shared__ __align__(16) float raw_lds[DH_][4];   // [e][gate]

  // Rr[j][m] = packed f16 pair (R[48u+2m][g][e3+j], R[48u+2m+1][g][e3+j])  (72 VGPRs)
  unsigned Rr[3][24];
  {
    const float* Rh = rk + (size_t)h * (DH_ * NTOT_);   // [k][g][e]
#pragma unroll
    for (int j = 0; j < 3; ++j) {
#pragma unroll
      for (int m = 0; m < 24; ++m) {
        const int k0 = 48 * u + 2 * m;
        float v0 = Rh[((size_t)k0 * 4 + g) * DH_ + e3 + j];
        float v1 = Rh[((size_t)(k0 + 1) * 4 + g) * DH_ + e3 + j];
        Rr[j][m] = packh2(v0, v1);
      }
    }
  }

  // gate-phase constants (valid for tid < 768, e = Q)
  float biasv[4] = {0.f, 0.f, 0.f, 0.f};
  if (tid < NTOT_) {
#pragma unroll
    for (int gg = 0; gg < 4; ++gg) biasv[gg] = rb[(gg * NH_ + h) * DH_ + Q];
  }
  if (tid < DH_) y_lds[tid] = (f16)0.f;

  float c = 0.f, nrm = 0.f, m = 0.f;
  short* Pc = P_ + (size_t)bid * S_ * NTOT_;
  short4v wxc = {};
  if (tid < NTOT_) wxc = *(const short4v*)(Pc + Q * 4);
  __syncthreads();

#pragma unroll 1
  for (int t = 0; t < S_; ++t) {
    // prefetch next-step Wx (quad-uniform 8B load; latency hidden under dots)
    short4v wxn = {};
    if (tid < NTOT_ && t + 1 < S_)
      wxn = *(const short4v*)(Pc + (size_t)(t + 1) * NTOT_ + Q * 4);

    // ---- dot phase: y k-quarter (96 B) via 6x b128; 72 dot2 ----
    const f16* yb = y_lds + 48 * u;
    float a0 = 0.f, a1 = 0.f, a2 = 0.f;
#pragma unroll
    for (int i = 0; i < 6; ++i) {
      uint4v yv = ((const uint4v*)yb)[i];
#pragma unroll
      for (int mm = 0; mm < 4; ++mm) {
        const unsigned yp = yv[mm];
        const int j = i * 4 + mm;
        a0 = DOT2(Rr[0][j], yp, a0);
        a1 = DOT2(Rr[1][j], yp, a1);
        a2 = DOT2(Rr[2][j], yp, a2);
      }
    }
    // quad butterfly: sum the 4 k-quarters (all 4 lanes end with full sums)
    a0 += qperm<0xB1>(a0);  a0 += qperm<0x4E>(a0);
    a1 += qperm<0xB1>(a1);  a1 += qperm<0x4E>(a1);
    a2 += qperm<0xB1>(a2);  a2 += qperm<0x4E>(a2);
    // lane u<3 publishes raw for output (e3+u, g)  (static select, no array idx)
    if (u < 3) {
      float av = (u == 0) ? a0 : (u == 1) ? a1 : a2;
      raw_lds[e3 + u][g] = av;
    }
    __syncthreads();

    // ---- gate phase: e = Q (tid<768), quad-redundant ----
    if (tid < NTOT_) {
      floatx4 r4 = *(const floatx4*)raw_lds[Q];
      float ir  = bs2f((unsigned short)wxc[0]) + r4[0] + biasv[0];
      float fr  = bs2f((unsigned short)wxc[1]) + r4[1] + biasv[1];
      float zr  = bs2f((unsigned short)wxc[2]) + r4[2] + biasv[2];
      float orr = bs2f((unsigned short)wxc[3]) + r4[3] + biasv[3];

      float lsf = fminf(fr, 0.f) - __logf(1.f + __expf(-fabsf(fr)));
      float lfm = m + lsf;
      float mnew = fmaxf(ir, lfm);
      float ig = __expf(ir - mnew);
      float fg = __expf(lfm - mnew);
      float e2z = __expf(2.f * zr);
      float tz = 1.f - 2.f / (e2z + 1.f);
      c   = fg * c + ig * tz;
      nrm = fg * nrm + ig;
      m = mnew;
      float sg = 1.f / (1.f + __expf(-orr));
      float y = sg * c / nrm;

      if (u == 0) {
        f16 yh = (f16)y;
        y_lds[Q] = yh;
        union { f16 hh; short ss; } uv; uv.hh = yh;
        Pc[(size_t)t * NTOT_ + Q] = uv.ss;   // y history (row already consumed)
      }
    }
    wxc = wxn;
    __syncthreads();
  }
}

// ---------------- K4: groupnorm over DH per (h,b,s) row ----------------
__global__ __launch_bounds__(256) void gnorm_kernel(
    const short* __restrict__ yws, const float* __restrict__ gnw,
    float* __restrict__ out)
{
  const int row = blockIdx.x * 4 + (threadIdx.x >> 6);   // (h,b,s), 0..131071
  const int l = threadIdx.x & 63;
  const int h = row >> 15;
  const int b = (row >> 12) & 7;
  const int s = row & (S_ - 1);
  const short* yr = yws + (size_t)row * NTOT_;
  float v[3];
  float su = 0.f, sq = 0.f;
#pragma unroll
  for (int j = 0; j < 3; ++j) {
    unsigned short u = (unsigned short)yr[l + j * 64];
    union { unsigned short u; f16 h; } cv; cv.u = u;
    v[j] = (float)cv.h;
    su += v[j]; sq += v[j] * v[j];
  }
  for (int off = 32; off; off >>= 1) {
    su += __shfl_xor(su, off);
    sq += __shfl_xor(sq, off);
  }
  float mean = su * (1.f / DH_);
  float var = sq * (1.f / DH_) - mean * mean;
  float rs = rsqrtf(var + 1e-5f);
  float* orow = out + ((size_t)b * S_ + s) * D_ + h * DH_;
#pragma unroll
  for (int j = 0; j < 3; ++j)
    orow[l + j * 64] = (v[j] - mean) * rs * gnw[h * DH_ + l + j * 64];
}

extern "C" void kernel_launch(void* const* d_in, const int* in_sizes, int n_in,
                              void* d_out, int out_size, void* d_ws, size_t ws_size,
                              hipStream_t stream) {
  const float* x   = (const float*)d_in[0];
  const float* cw  = (const float*)d_in[1];
  const float* cb  = (const float*)d_in[2];
  const float* wf  = (const float*)d_in[3];
  const float* wi  = (const float*)d_in[4];
  const float* wz  = (const float*)d_in[5];
  const float* wo  = (const float*)d_in[6];
  const float* rk  = (const float*)d_in[7];
  const float* rb  = (const float*)d_in[8];
  const float* gnw = (const float*)d_in[9];
  float* out = (float*)d_out;

  // Workspace: P (bf16 Wx, [h][b][s][768]) = 201,326,592 B; Wbf = 1,179,648 B
  short* P   = (short*)d_ws;
  short* Wbf = (short*)((char*)d_ws + (size_t)201326592);
  // Reuse d_out (100,663,296 B) as scratch for bf16 x / conv(x); gnorm overwrites it.
  short* xb  = (short*)d_out;
  short* xcb = (short*)((char*)d_out + (size_t)50331648);

  wconv_kernel<<<dim3(2304), 256, 0, stream>>>(wf, wi, wz, wo, Wbf);
  conv_silu_kernel<<<dim3(512), 256, 0, stream>>>(x, cw, cb, xb, xcb);
  proj_kernel<<<dim3(128, 16), 256, 0, stream>>>(xb, xcb, Wbf, P);
  scan_kernel<<<dim3(32), 1024, 0, stream>>>(P, rk, rb);
  gnorm_kernel<<<dim3(32768), 256, 0, stream>>>(P, gnw, out);
}

// Round 8
// 5642.860 us; speedup vs baseline: 1.0722x; 1.0722x over previous
//
#include <hip/hip_runtime.h>
#include <hip/hip_bf16.h>
#include <math.h>

#define B_ 8
#define S_ 4096
#define D_ 768
#define NH_ 4
#define DH_ 192
#define NTOT_ 768   // 4*DH_

typedef __attribute__((ext_vector_type(8))) short short8;
typedef __attribute__((ext_vector_type(4))) float floatx4;
typedef __attribute__((ext_vector_type(4))) short short4v;
typedef __attribute__((ext_vector_type(4))) unsigned int uint4v;
typedef _Float16 f16;

__device__ __forceinline__ short f2bs(float f) {
  union { float f; unsigned u; } v; v.f = f;
  unsigned r = v.u + 0x7FFFu + ((v.u >> 16) & 1u);
  return (short)(r >> 16);
}
__device__ __forceinline__ float bs2f(unsigned short s) {
  union { unsigned u; float f; } v; v.u = ((unsigned)s) << 16;
  return v.f;
}
__device__ __forceinline__ unsigned packh2(float lo, float hi) {
  union { f16 h[2]; unsigned u; } x;
  x.h[0] = (f16)lo; x.h[1] = (f16)hi;
  return x.u;
}

// forced v_dot2_f32_f16 (f32 accumulate)
__device__ __forceinline__ float DOT2(unsigned r, unsigned y, float acc) {
  asm("v_dot2_f32_f16 %0, %1, %2, %0" : "+v"(acc) : "v"(r), "v"(y));
  return acc;
}

// quad-perm DPP (register-only cross-lane within quad)
template<int CTRL>
__device__ __forceinline__ float qperm(float x) {
  return __int_as_float(__builtin_amdgcn_mov_dpp(__float_as_int(x), CTRL, 0xf, 0xf, true));
}

// ---------------- K0: weights -> bf16, fragment-friendly [hg][o][d] ----------------
__global__ __launch_bounds__(256) void wconv_kernel(
    const float* __restrict__ wf, const float* __restrict__ wi,
    const float* __restrict__ wz, const float* __restrict__ wo,
    short* __restrict__ Wbf)
{
  int idx = blockIdx.x * 256 + threadIdx.x;      // < 16*36864
  int hg = idx / (DH_ * DH_);
  int r  = idx % (DH_ * DH_);
  int h = hg >> 2, g = hg & 3;
  const float* W = (g == 0) ? wf : (g == 1) ? wi : (g == 2) ? wz : wo;
  Wbf[idx] = f2bs(W[(size_t)h * DH_ * DH_ + r]);
}

// ---------------- K1: depthwise causal conv + SiLU; also bf16 copy of x ----------------
__global__ __launch_bounds__(256) void conv_silu_kernel(
    const float* __restrict__ x, const float* __restrict__ cw, const float* __restrict__ cb,
    short* __restrict__ xb, short* __restrict__ xcb)
{
  const int b  = blockIdx.x / (S_ / 64);
  const int s0 = (blockIdx.x % (S_ / 64)) * 64;
  const int tid = threadIdx.x;
  float wv[3][4], bias[3], win[3][3];
  for (int j = 0; j < 3; ++j) {
    int d = tid + j * 256;
    for (int k = 0; k < 4; ++k) wv[j][k] = cw[d * 4 + k];
    bias[j] = cb[d];
    for (int p = 0; p < 3; ++p) {
      int s = s0 - 3 + p;
      win[j][p] = (s >= 0) ? x[((size_t)b * S_ + s) * D_ + d] : 0.f;
    }
  }
  for (int i = 0; i < 64; ++i) {
    size_t base = ((size_t)b * S_ + (s0 + i)) * D_;
    for (int j = 0; j < 3; ++j) {
      int d = tid + j * 256;
      float xc = x[base + d];
      float a = bias[j] + win[j][0] * wv[j][0] + win[j][1] * wv[j][1]
                        + win[j][2] * wv[j][2] + xc * wv[j][3];
      float sv = a / (1.f + __expf(-a));
      xb[base + d]  = f2bs(xc);
      xcb[base + d] = f2bs(sv);
      win[j][0] = win[j][1]; win[j][1] = win[j][2]; win[j][2] = xc;
    }
  }
}

// ---------------- K2: headwise projections -> P[h][b][s][e*4+g] (bf16) ----------------
__global__ __launch_bounds__(256) void proj_kernel(
    const short* __restrict__ xb, const short* __restrict__ xcb,
    const short* __restrict__ Wbf, short* __restrict__ P)
{
  const int hg = blockIdx.y;
  const int h = hg >> 2, g = hg & 3;
  const short* A  = (g < 2) ? xcb : xb;           // gi,gf from conv(x); gz,go from x
  const short* Wb = Wbf + (size_t)hg * (DH_ * DH_);
  const int tid = threadIdx.x, w = tid >> 6, l = tid & 63;
  const int l15 = l & 15, lg = l >> 4;
  const int R0 = blockIdx.x * 256 + w * 64;

  for (int mp = 0; mp < 2; ++mp) {
    const int rb0 = R0 + mp * 32;
    floatx4 acc[2][12];
    for (int u = 0; u < 2; ++u)
      for (int nt = 0; nt < 12; ++nt) acc[u][nt] = (floatx4){0.f, 0.f, 0.f, 0.f};
    const short* Ar = A + (size_t)(rb0 + l15) * D_ + h * DH_ + lg * 8;
    const short* Bp = Wb + l15 * DH_ + lg * 8;
    for (int kk = 0; kk < 6; ++kk) {
      short8 a0 = *(const short8*)(Ar + kk * 32);
      short8 a1 = *(const short8*)(Ar + (size_t)16 * D_ + kk * 32);
      for (int nt = 0; nt < 12; ++nt) {
        short8 bf = *(const short8*)(Bp + nt * 16 * DH_ + kk * 32);
        acc[0][nt] = __builtin_amdgcn_mfma_f32_16x16x32_bf16(a0, bf, acc[0][nt], 0, 0, 0);
        acc[1][nt] = __builtin_amdgcn_mfma_f32_16x16x32_bf16(a1, bf, acc[1][nt], 0, 0, 0);
      }
    }
    for (int u = 0; u < 2; ++u) {
      for (int q = 0; q < 4; ++q) {
        int row = rb0 + u * 16 + lg * 4 + q;
        int s = row & (S_ - 1);
        int bb = row >> 12;
        // packed gate-interleaved layout: column e*4 + g, e = l15 + nt*16
        size_t ob = (((size_t)h * B_ + bb) * S_ + s) * NTOT_ + l15 * 4 + g;
        for (int nt = 0; nt < 12; ++nt) P[ob + nt * 64] = f2bs(acc[u][nt][q]);
      }
    }
  }
}

// ---------------- K3: sequential sLSTM scan (asm dot2, quad k-split) ----------------
// 768 threads per (h,b) chain. Lane (e,q) = (t0>>2, t0&3): owns k-slice
// [48q,48q+48) for all 4 gate columns of element e.
// OCCUPANCY PIN: 96KB static LDS -> 1 WG/CU (160KB pool) -> 12 waves ->
// register budget ~170/wave, so the 96-reg Rr array stays architectural.
// (R5-R7 evidence: allocator otherwise targets 2 WG/CU and shuttles Rr.)
#define SCAN_LDS_BYTES 98304
__global__ __launch_bounds__(768)
__attribute__((amdgpu_waves_per_eu(3, 3)))
void scan_kernel(short* P_, const float* __restrict__ rk, const float* __restrict__ rb)
{
  const int bid = blockIdx.x;      // 0..31: chain; h = bid>>3, b = bid&7
  const int h = bid >> 3;
  const int t0 = threadIdx.x;      // 0..767
  const int e = t0 >> 2, q = t0 & 3;

  __shared__ __align__(16) char shbuf[SCAN_LDS_BYTES];   // occupancy pin
  f16 (*y_lds)[DH_] = (f16 (*)[DH_])shbuf;               // y_lds[2][DH_] aliased inside

  // Rr[g][j] = packed f16 pair (R[48q+2j][g][e], R[48q+2j+1][g][e])  (96 VGPRs)
  unsigned Rr[4][24];
  {
    const float* Rh = rk + (size_t)h * (DH_ * NTOT_);   // [k][g][e]
#pragma unroll
    for (int j = 0; j < 24; ++j) {
      const int k0 = 48 * q + 2 * j;
#pragma unroll
      for (int g = 0; g < 4; ++g) {
        float v0 = Rh[((size_t)k0 * 4 + g) * DH_ + e];
        float v1 = Rh[((size_t)(k0 + 1) * 4 + g) * DH_ + e];
        Rr[g][j] = packh2(v0, v1);
      }
    }
  }
  float biasv[4];
#pragma unroll
  for (int g = 0; g < 4; ++g) biasv[g] = rb[(g * NH_ + h) * DH_ + e];

  if (t0 < DH_) y_lds[0][t0] = (f16)0.f;

  float c = 0.f, nrm = 0.f, m = 0.f;
  short* Pc = P_ + (size_t)bid * S_ * NTOT_;
  short4v wxc = *(const short4v*)(Pc + e * 4);
  __syncthreads();

#pragma unroll 1
  for (int t = 0; t < S_; ++t) {
    short4v wxn = {};
    if (t + 1 < S_) wxn = *(const short4v*)(Pc + (size_t)(t + 1) * NTOT_ + e * 4);

    // y slice: 48 halves = 24 dwords via 6x ds_read_b128; consumed as raw dwords
    const f16* yb = &y_lds[t & 1][q * 48];
    float a0 = 0.f, a1 = 0.f, a2 = 0.f, a3 = 0.f;
#pragma unroll
    for (int i = 0; i < 6; ++i) {
      uint4v yv = ((const uint4v*)yb)[i];
#pragma unroll
      for (int u = 0; u < 4; ++u) {
        const unsigned yp = yv[u];
        const int j = i * 4 + u;
        a0 = DOT2(Rr[0][j], yp, a0);
        a1 = DOT2(Rr[1][j], yp, a1);
        a2 = DOT2(Rr[2][j], yp, a2);
        a3 = DOT2(Rr[3][j], yp, a3);
      }
    }
    // quad butterfly: sum partials over the 4 k-slices (register-only)
    a0 += qperm<0xB1>(a0);  a0 += qperm<0x4E>(a0);
    a1 += qperm<0xB1>(a1);  a1 += qperm<0x4E>(a1);
    a2 += qperm<0xB1>(a2);  a2 += qperm<0x4E>(a2);
    a3 += qperm<0xB1>(a3);  a3 += qperm<0x4E>(a3);

    float ir  = bs2f((unsigned short)wxc[0]) + a0 + biasv[0];
    float fr  = bs2f((unsigned short)wxc[1]) + a1 + biasv[1];
    float zr  = bs2f((unsigned short)wxc[2]) + a2 + biasv[2];
    float orr = bs2f((unsigned short)wxc[3]) + a3 + biasv[3];

    float lsf = fminf(fr, 0.f) - __logf(1.f + __expf(-fabsf(fr)));
    float lfm = m + lsf;
    float mnew = fmaxf(ir, lfm);
    float ig = __expf(ir - mnew);
    float fg = __expf(lfm - mnew);
    float e2z = __expf(2.f * zr);
    float tz = 1.f - 2.f / (e2z + 1.f);
    c   = fg * c + ig * tz;
    nrm = fg * nrm + ig;
    m = mnew;
    float sg = 1.f / (1.f + __expf(-orr));
    float y = sg * c / nrm;

    f16 yh = (f16)y;
    if (q == 0) {
      y_lds[(t & 1) ^ 1][e] = yh;
      union { f16 hh; short ss; } uv; uv.hh = yh;
      Pc[(size_t)t * NTOT_ + e] = uv.ss;   // y history (row already consumed)
    }
    wxc = wxn;
    __syncthreads();
  }
}

// ---------------- K4: groupnorm over DH per (h,b,s) row ----------------
__global__ __launch_bounds__(256) void gnorm_kernel(
    const short* __restrict__ yws, const float* __restrict__ gnw,
    float* __restrict__ out)
{
  const int row = blockIdx.x * 4 + (threadIdx.x >> 6);   // (h,b,s), 0..131071
  const int l = threadIdx.x & 63;
  const int h = row >> 15;
  const int b = (row >> 12) & 7;
  const int s = row & (S_ - 1);
  const short* yr = yws + (size_t)row * NTOT_;
  float v[3];
  float su = 0.f, sq = 0.f;
#pragma unroll
  for (int j = 0; j < 3; ++j) {
    unsigned short u = (unsigned short)yr[l + j * 64];
    union { unsigned short u; f16 h; } cv; cv.u = u;
    v[j] = (float)cv.h;
    su += v[j]; sq += v[j] * v[j];
  }
  for (int off = 32; off; off >>= 1) {
    su += __shfl_xor(su, off);
    sq += __shfl_xor(sq, off);
  }
  float mean = su * (1.f / DH_);
  float var = sq * (1.f / DH_) - mean * mean;
  float rs = rsqrtf(var + 1e-5f);
  float* orow = out + ((size_t)b * S_ + s) * D_ + h * DH_;
#pragma unroll
  for (int j = 0; j < 3; ++j)
    orow[l + j * 64] = (v[j] - mean) * rs * gnw[h * DH_ + l + j * 64];
}

extern "C" void kernel_launch(void* const* d_in, const int* in_sizes, int n_in,
                              void* d_out, int out_size, void* d_ws, size_t ws_size,
                              hipStream_t stream) {
  const float* x   = (const float*)d_in[0];
  const float* cw  = (const float*)d_in[1];
  const float* cb  = (const float*)d_in[2];
  const float* wf  = (const float*)d_in[3];
  const float* wi  = (const float*)d_in[4];
  const float* wz  = (const float*)d_in[5];
  const float* wo  = (const float*)d_in[6];
  const float* rk  = (const float*)d_in[7];
  const float* rb  = (const float*)d_in[8];
  const float* gnw = (const float*)d_in[9];
  float* out = (float*)d_out;

  // Workspace: P (bf16 Wx, [h][b][s][768]) = 201,326,592 B; Wbf = 1,179,648 B
  short* P   = (short*)d_ws;
  short* Wbf = (short*)((char*)d_ws + (size_t)201326592);
  // Reuse d_out (100,663,296 B) as scratch for bf16 x / conv(x); gnorm overwrites it.
  short* xb  = (short*)d_out;
  short* xcb = (short*)((char*)d_out + (size_t)50331648);

  wconv_kernel<<<dim3(2304), 256, 0, stream>>>(wf, wi, wz, wo, Wbf);
  conv_silu_kernel<<<dim3(512), 256, 0, stream>>>(x, cw, cb, xb, xcb);
  proj_kernel<<<dim3(128, 16), 256, 0, stream>>>(xb, xcb, Wbf, P);
  scan_kernel<<<dim3(32), 768, 0, stream>>>(P, rk, rb);
  gnorm_kernel<<<dim3(32768), 256, 0, stream>>>(P, gnw, out);
}

// Round 9
// 4955.413 us; speedup vs baseline: 1.2210x; 1.1387x over previous
//
#include <hip/hip_runtime.h>
#include <hip/hip_bf16.h>
#include <math.h>

#define B_ 8
#define S_ 4096
#define D_ 768
#define NH_ 4
#define DH_ 192
#define NTOT_ 768   // 4*DH_

typedef __attribute__((ext_vector_type(8))) short short8;
typedef __attribute__((ext_vector_type(4))) float floatx4;
typedef __attribute__((ext_vector_type(4))) short short4v;
typedef __attribute__((ext_vector_type(4))) unsigned int uint4v;
typedef _Float16 f16;

__device__ __forceinline__ short f2bs(float f) {
  union { float f; unsigned u; } v; v.f = f;
  unsigned r = v.u + 0x7FFFu + ((v.u >> 16) & 1u);
  return (short)(r >> 16);
}
__device__ __forceinline__ float bs2f(unsigned short s) {
  union { unsigned u; float f; } v; v.u = ((unsigned)s) << 16;
  return v.f;
}
__device__ __forceinline__ unsigned packh2(float lo, float hi) {
  union { f16 h[2]; unsigned u; } x;
  x.h[0] = (f16)lo; x.h[1] = (f16)hi;
  return x.u;
}

// forced v_dot2_f32_f16 (f32 accumulate)
__device__ __forceinline__ float DOT2(unsigned r, unsigned y, float acc) {
  asm("v_dot2_f32_f16 %0, %1, %2, %0" : "+v"(acc) : "v"(r), "v"(y));
  return acc;
}

// quad-perm DPP (register-only cross-lane within quad)
template<int CTRL>
__device__ __forceinline__ float qperm(float x) {
  return __int_as_float(__builtin_amdgcn_mov_dpp(__float_as_int(x), CTRL, 0xf, 0xf, true));
}

// ---------------- K0: weights -> bf16, fragment-friendly [hg][o][d] ----------------
__global__ __launch_bounds__(256) void wconv_kernel(
    const float* __restrict__ wf, const float* __restrict__ wi,
    const float* __restrict__ wz, const float* __restrict__ wo,
    short* __restrict__ Wbf)
{
  int idx = blockIdx.x * 256 + threadIdx.x;      // < 16*36864
  int hg = idx / (DH_ * DH_);
  int r  = idx % (DH_ * DH_);
  int h = hg >> 2, g = hg & 3;
  const float* W = (g == 0) ? wf : (g == 1) ? wi : (g == 2) ? wz : wo;
  Wbf[idx] = f2bs(W[(size_t)h * DH_ * DH_ + r]);
}

// ---------------- K1: depthwise causal conv + SiLU; also bf16 copy of x ----------------
__global__ __launch_bounds__(256) void conv_silu_kernel(
    const float* __restrict__ x, const float* __restrict__ cw, const float* __restrict__ cb,
    short* __restrict__ xb, short* __restrict__ xcb)
{
  const int b  = blockIdx.x / (S_ / 64);
  const int s0 = (blockIdx.x % (S_ / 64)) * 64;
  const int tid = threadIdx.x;
  float wv[3][4], bias[3], win[3][3];
  for (int j = 0; j < 3; ++j) {
    int d = tid + j * 256;
    for (int k = 0; k < 4; ++k) wv[j][k] = cw[d * 4 + k];
    bias[j] = cb[d];
    for (int p = 0; p < 3; ++p) {
      int s = s0 - 3 + p;
      win[j][p] = (s >= 0) ? x[((size_t)b * S_ + s) * D_ + d] : 0.f;
    }
  }
  for (int i = 0; i < 64; ++i) {
    size_t base = ((size_t)b * S_ + (s0 + i)) * D_;
    for (int j = 0; j < 3; ++j) {
      int d = tid + j * 256;
      float xc = x[base + d];
      float a = bias[j] + win[j][0] * wv[j][0] + win[j][1] * wv[j][1]
                        + win[j][2] * wv[j][2] + xc * wv[j][3];
      float sv = a / (1.f + __expf(-a));
      xb[base + d]  = f2bs(xc);
      xcb[base + d] = f2bs(sv);
      win[j][0] = win[j][1]; win[j][1] = win[j][2]; win[j][2] = xc;
    }
  }
}

// ---------------- K2: headwise projections (+r_bias folded) -> P[h][b][s][e*4+g] ----
__global__ __launch_bounds__(256) void proj_kernel(
    const short* __restrict__ xb, const short* __restrict__ xcb,
    const short* __restrict__ Wbf, const float* __restrict__ rb,
    short* __restrict__ P)
{
  const int hg = blockIdx.y;
  const int h = hg >> 2, g = hg & 3;
  const short* A  = (g < 2) ? xcb : xb;           // gi,gf from conv(x); gz,go from x
  const short* Wb = Wbf + (size_t)hg * (DH_ * DH_);
  const int tid = threadIdx.x, w = tid >> 6, l = tid & 63;
  const int l15 = l & 15, lg = l >> 4;
  const int R0 = blockIdx.x * 256 + w * 64;

  float rbv[12];
#pragma unroll
  for (int nt = 0; nt < 12; ++nt)
    rbv[nt] = rb[(g * NH_ + h) * DH_ + l15 + nt * 16];

  for (int mp = 0; mp < 2; ++mp) {
    const int rb0 = R0 + mp * 32;
    floatx4 acc[2][12];
    for (int u = 0; u < 2; ++u)
      for (int nt = 0; nt < 12; ++nt) acc[u][nt] = (floatx4){0.f, 0.f, 0.f, 0.f};
    const short* Ar = A + (size_t)(rb0 + l15) * D_ + h * DH_ + lg * 8;
    const short* Bp = Wb + l15 * DH_ + lg * 8;
    for (int kk = 0; kk < 6; ++kk) {
      short8 a0 = *(const short8*)(Ar + kk * 32);
      short8 a1 = *(const short8*)(Ar + (size_t)16 * D_ + kk * 32);
      for (int nt = 0; nt < 12; ++nt) {
        short8 bf = *(const short8*)(Bp + nt * 16 * DH_ + kk * 32);
        acc[0][nt] = __builtin_amdgcn_mfma_f32_16x16x32_bf16(a0, bf, acc[0][nt], 0, 0, 0);
        acc[1][nt] = __builtin_amdgcn_mfma_f32_16x16x32_bf16(a1, bf, acc[1][nt], 0, 0, 0);
      }
    }
    for (int u = 0; u < 2; ++u) {
      for (int q = 0; q < 4; ++q) {
        int row = rb0 + u * 16 + lg * 4 + q;
        int s = row & (S_ - 1);
        int bb = row >> 12;
        // packed gate-interleaved layout: column e*4 + g, e = l15 + nt*16
        size_t ob = (((size_t)h * B_ + bb) * S_ + s) * NTOT_ + l15 * 4 + g;
        for (int nt = 0; nt < 12; ++nt)
          P[ob + nt * 64] = f2bs(acc[u][nt][q] + rbv[nt]);
      }
    }
  }
}

// ---------------- K3: sequential sLSTM scan (hybrid reg+LDS R storage) ----------------
// 768 threads per (h,b) chain. Lane (e,q) = (t0>>2, t0&3): k-slice [48q,48q+48)
// for all 4 gates of element e.
// R storage designed FOR the allocator's 84-VGPR target (R3-R8: it will NOT give
// more): gates 0,1 in registers (48 dwords); gates 2,3 in LDS as f16 (144 KB),
// chunk-interleaved RL[c][lane][16B] so reads are conflict-free ds_read_b128.
// Bias pre-folded into P by proj_kernel. 148 KB LDS also pins 1 WG/CU.
#define RL_BYTES 147456          // 12 chunks * 768 lanes * 16 B
#define CHUNK_B  12288           // 768 lanes * 16 B
__global__ __launch_bounds__(768)
void scan_kernel(short* P_, const float* __restrict__ rk)
{
  const int bid = blockIdx.x;      // 0..31: chain; h = bid>>3, b = bid&7
  const int h = bid >> 3;
  const int t0 = threadIdx.x;      // 0..767
  const int e = t0 >> 2, q = t0 & 3;

  __shared__ __align__(16) char shbuf[RL_BYTES + 2 * DH_ * 2];
  f16* ybuf = (f16*)(shbuf + RL_BYTES);          // y dbuf [2][DH_]

  const float* Rh = rk + (size_t)h * (DH_ * NTOT_);   // [k][g][e]

  // registers: gates 0,1  (48 dwords)
  unsigned Rr[2][24];
#pragma unroll
  for (int j = 0; j < 24; ++j) {
    const int k0 = 48 * q + 2 * j;
#pragma unroll
    for (int g = 0; g < 2; ++g) {
      float v0 = Rh[((size_t)k0 * 4 + g) * DH_ + e];
      float v1 = Rh[((size_t)(k0 + 1) * 4 + g) * DH_ + e];
      Rr[g][j] = packh2(v0, v1);
    }
  }
  // LDS: gates 2,3 -> chunk c (0..5: gate2, 6..11: gate3), 16B per lane per chunk
#pragma unroll
  for (int c = 0; c < 12; ++c) {
    const int gate = 2 + (c >= 6);
    const int m0 = (c % 6) * 4;
    uint4v blk;
#pragma unroll
    for (int j = 0; j < 4; ++j) {
      const int k0 = 48 * q + 2 * (m0 + j);
      blk[j] = packh2(Rh[((size_t)k0 * 4 + gate) * DH_ + e],
                      Rh[((size_t)(k0 + 1) * 4 + gate) * DH_ + e]);
    }
    *(uint4v*)(shbuf + c * CHUNK_B + t0 * 16) = blk;
  }

  if (t0 < DH_) ybuf[t0] = (f16)0.f;

  float c = 0.f, nrm = 0.f, m = 0.f;
  short* Pc = P_ + (size_t)bid * S_ * NTOT_;
  short4v wxc = *(const short4v*)(Pc + e * 4);
  __syncthreads();

  const char* rlz = shbuf + t0 * 16;             // gate2 chunks at +c*CHUNK_B
  const char* rlo = rlz + 6 * CHUNK_B;           // gate3 chunks

#pragma unroll 1
  for (int t = 0; t < S_; ++t) {
    short4v wxn = {};
    if (t + 1 < S_) wxn = *(const short4v*)(Pc + (size_t)(t + 1) * NTOT_ + e * 4);

    const f16* yb = ybuf + (t & 1) * DH_ + q * 48;
    float a0 = 0.f, a1 = 0.f, a2 = 0.f, a3 = 0.f;
#pragma unroll
    for (int i = 0; i < 6; ++i) {
      uint4v Y = *(const uint4v*)(yb + i * 8);
      uint4v Z = *(const uint4v*)(rlz + i * CHUNK_B);
      uint4v O = *(const uint4v*)(rlo + i * CHUNK_B);
#pragma unroll
      for (int u = 0; u < 4; ++u) {
        const int j = i * 4 + u;
        a0 = DOT2(Rr[0][j], Y[u], a0);
        a1 = DOT2(Rr[1][j], Y[u], a1);
        a2 = DOT2(Z[u], Y[u], a2);
        a3 = DOT2(O[u], Y[u], a3);
      }
    }
    // quad butterfly: sum partials over the 4 k-slices (register-only)
    a0 += qperm<0xB1>(a0);  a0 += qperm<0x4E>(a0);
    a1 += qperm<0xB1>(a1);  a1 += qperm<0x4E>(a1);
    a2 += qperm<0xB1>(a2);  a2 += qperm<0x4E>(a2);
    a3 += qperm<0xB1>(a3);  a3 += qperm<0x4E>(a3);

    float ir  = bs2f((unsigned short)wxc[0]) + a0;
    float fr  = bs2f((unsigned short)wxc[1]) + a1;
    float zr  = bs2f((unsigned short)wxc[2]) + a2;
    float orr = bs2f((unsigned short)wxc[3]) + a3;

    float lsf = fminf(fr, 0.f) - __logf(1.f + __expf(-fabsf(fr)));
    float lfm = m + lsf;
    float mnew = fmaxf(ir, lfm);
    float ig = __expf(ir - mnew);
    float fg = __expf(lfm - mnew);
    float e2z = __expf(2.f * zr);
    float tz = 1.f - 2.f * __builtin_amdgcn_rcpf(e2z + 1.f);
    c   = fg * c + ig * tz;
    nrm = fg * nrm + ig;
    m = mnew;
    float sg = __builtin_amdgcn_rcpf(1.f + __expf(-orr));
    float y = sg * c * __builtin_amdgcn_rcpf(nrm);

    f16 yh = (f16)y;
    if (q == 0) {
      ybuf[((t & 1) ^ 1) * DH_ + e] = yh;
      union { f16 hh; short ss; } uv; uv.hh = yh;
      Pc[(size_t)t * NTOT_ + e] = uv.ss;   // y history (row already consumed)
    }
    wxc = wxn;
    __syncthreads();
  }
}

// ---------------- K4: groupnorm over DH per (h,b,s) row ----------------
__global__ __launch_bounds__(256) void gnorm_kernel(
    const short* __restrict__ yws, const float* __restrict__ gnw,
    float* __restrict__ out)
{
  const int row = blockIdx.x * 4 + (threadIdx.x >> 6);   // (h,b,s), 0..131071
  const int l = threadIdx.x & 63;
  const int h = row >> 15;
  const int b = (row >> 12) & 7;
  const int s = row & (S_ - 1);
  const short* yr = yws + (size_t)row * NTOT_;
  float v[3];
  float su = 0.f, sq = 0.f;
#pragma unroll
  for (int j = 0; j < 3; ++j) {
    unsigned short u = (unsigned short)yr[l + j * 64];
    union { unsigned short u; f16 h; } cv; cv.u = u;
    v[j] = (float)cv.h;
    su += v[j]; sq += v[j] * v[j];
  }
  for (int off = 32; off; off >>= 1) {
    su += __shfl_xor(su, off);
    sq += __shfl_xor(sq, off);
  }
  float mean = su * (1.f / DH_);
  float var = sq * (1.f / DH_) - mean * mean;
  float rs = rsqrtf(var + 1e-5f);
  float* orow = out + ((size_t)b * S_ + s) * D_ + h * DH_;
#pragma unroll
  for (int j = 0; j < 3; ++j)
    orow[l + j * 64] = (v[j] - mean) * rs * gnw[h * DH_ + l + j * 64];
}

extern "C" void kernel_launch(void* const* d_in, const int* in_sizes, int n_in,
                              void* d_out, int out_size, void* d_ws, size_t ws_size,
                              hipStream_t stream) {
  const float* x   = (const float*)d_in[0];
  const float* cw  = (const float*)d_in[1];
  const float* cb  = (const float*)d_in[2];
  const float* wf  = (const float*)d_in[3];
  const float* wi  = (const float*)d_in[4];
  const float* wz  = (const float*)d_in[5];
  const float* wo  = (const float*)d_in[6];
  const float* rk  = (const float*)d_in[7];
  const float* rb  = (const float*)d_in[8];
  const float* gnw = (const float*)d_in[9];
  float* out = (float*)d_out;

  // Workspace: P (bf16 Wx, [h][b][s][768]) = 201,326,592 B; Wbf = 1,179,648 B
  short* P   = (short*)d_ws;
  short* Wbf = (short*)((char*)d_ws + (size_t)201326592);
  // Reuse d_out (100,663,296 B) as scratch for bf16 x / conv(x); gnorm overwrites it.
  short* xb  = (short*)d_out;
  short* xcb = (short*)((char*)d_out + (size_t)50331648);

  wconv_kernel<<<dim3(2304), 256, 0, stream>>>(wf, wi, wz, wo, Wbf);
  conv_silu_kernel<<<dim3(512), 256, 0, stream>>>(x, cw, cb, xb, xcb);
  proj_kernel<<<dim3(128, 16), 256, 0, stream>>>(xb, xcb, Wbf, rb, P);
  scan_kernel<<<dim3(32), 768, 0, stream>>>(P, rk);
  gnorm_kernel<<<dim3(32768), 256, 0, stream>>>(P, gnw, out);
}